// Round 1
// baseline (918.954 us; speedup 1.0000x reference)
//
#include <hip/hip_runtime.h>

#define N_NODES 50000
#define N_EDGES 400000
#define D 512
#define NCLS 40

typedef __attribute__((ext_vector_type(8))) __bf16 bf16x8;
typedef __attribute__((ext_vector_type(4))) float f32x4;
typedef __attribute__((ext_vector_type(4))) float float4v;
typedef __attribute__((ext_vector_type(8))) unsigned short ushort8v;
typedef __attribute__((ext_vector_type(4))) unsigned short ushort4v;

__device__ __forceinline__ float bf2f(unsigned short u) {
  union { unsigned int i; float f; } v; v.i = ((unsigned int)u) << 16; return v.f;
}
__device__ __forceinline__ unsigned short f2bf(float f) {
  union { float f; unsigned int i; } v; v.f = f;
  unsigned int u = v.i;
  u += 0x7fffu + ((u >> 16) & 1u);  // round-nearest-even
  return (unsigned short)(u >> 16);
}

// ---------------- CSR build ----------------
__global__ void hist_kernel(const int* __restrict__ dst, int* __restrict__ counts) {
  int e = blockIdx.x * blockDim.x + threadIdx.x;
  if (e < N_EDGES) atomicAdd(&counts[dst[e]], 1);
}

__global__ void scan_kernel(const int* __restrict__ counts, int* __restrict__ row_ptr,
                            int* __restrict__ cursor) {
  __shared__ int sdata[1024];
  __shared__ int carry;
  if (threadIdx.x == 0) { carry = 0; row_ptr[0] = 0; }
  __syncthreads();
  for (int base = 0; base < N_NODES; base += 1024) {
    int i = base + threadIdx.x;
    int v = (i < N_NODES) ? counts[i] : 0;
    sdata[threadIdx.x] = v;
    __syncthreads();
    for (int offt = 1; offt < 1024; offt <<= 1) {
      int t = (threadIdx.x >= offt) ? sdata[threadIdx.x - offt] : 0;
      __syncthreads();
      sdata[threadIdx.x] += t;
      __syncthreads();
    }
    if (i < N_NODES) {
      int incl = sdata[threadIdx.x];
      row_ptr[i + 1] = carry + incl;
      cursor[i] = carry + incl - v;  // exclusive prefix
    }
    __syncthreads();
    if (threadIdx.x == 1023) carry += sdata[1023];
    __syncthreads();
  }
}

__global__ void fill_kernel(const int* __restrict__ src, const int* __restrict__ dst,
                            int* __restrict__ cursor, int* __restrict__ esrc) {
  int e = blockIdx.x * blockDim.x + threadIdx.x;
  if (e < N_EDGES) {
    int pos = atomicAdd(&cursor[dst[e]], 1);
    esrc[pos] = src[e];
  }
}

// ---------------- conversions ----------------
__global__ void cvt_feat_kernel(const float* __restrict__ feat, unsigned short* __restrict__ hb) {
  size_t i = (size_t)(blockIdx.x * blockDim.x + threadIdx.x) * 4;
  if (i < (size_t)N_NODES * D) {
    float4v v = *(const float4v*)&feat[i];
    ushort4v o;
    o[0] = f2bf(v[0]); o[1] = f2bf(v[1]); o[2] = f2bf(v[2]); o[3] = f2bf(v[3]);
    *(ushort4v*)&hb[i] = o;
  }
}

// Wt[n*512 + k] = bf16(W[k*512 + n])   (transpose so GEMM B-frag reads are contiguous in k)
__global__ void cvt_w_kernel(const float* __restrict__ W, unsigned short* __restrict__ Wt) {
  int i = blockIdx.x * blockDim.x + threadIdx.x;
  int n = i >> 9, k = i & 511;
  Wt[i] = f2bf(W[k * D + n]);
}

// ---------------- aggregation: z = h + sum_{e: dst=i} h[src[e]] ----------------
// one wave per node; lane covers dims [lane*8, lane*8+8) -> each row gather is one
// fully-coalesced 1KB wave read (64 lanes x 16B).
__global__ __launch_bounds__(256) void agg_kernel(const unsigned short* __restrict__ hb,
    const int* __restrict__ row_ptr, const int* __restrict__ esrc,
    unsigned short* __restrict__ zb) {
  int w = threadIdx.x >> 6, lane = threadIdx.x & 63;
  int node = blockIdx.x * 4 + w;
  int col = lane * 8;
  float acc[8];
  ushort8v v = *(const ushort8v*)&hb[(size_t)node * D + col];
#pragma unroll
  for (int t = 0; t < 8; ++t) acc[t] = bf2f(v[t]);
  int s = row_ptr[node], e = row_ptr[node + 1];
  for (int j = s; j < e; ++j) {
    int sn = esrc[j];
    ushort8v nv = *(const ushort8v*)&hb[(size_t)sn * D + col];
#pragma unroll
    for (int t = 0; t < 8; ++t) acc[t] += bf2f(nv[t]);
  }
  ushort8v o;
#pragma unroll
  for (int t = 0; t < 8; ++t) o[t] = f2bf(acc[t]);
  *(ushort8v*)&zb[(size_t)node * D + col] = o;
}

// ---------------- GEMM: Hout = relu(Z @ W + b), bf16 MFMA, m97 structure ----------------
// Z [M][512] bf16 row-major; Wt [512 n][512 k] bf16 (W transposed); Hout [M][512] bf16.
// 128x128 block tile, 256 threads = 4 waves in 2x2, each wave 64x64 via 4x4 mfma_16x16x32.
__global__ __launch_bounds__(256) void gemm_kernel(
    const unsigned short* __restrict__ Z, const unsigned short* __restrict__ Wt,
    const float* __restrict__ bias, unsigned short* __restrict__ Hout, int M) {
  __shared__ unsigned short As[128 * 32];
  __shared__ unsigned short Bs[128 * 32];
  const int m0 = blockIdx.x * 128;
  const int n0 = blockIdx.y * 128;
  const int tid = threadIdx.x;
  const int lane = tid & 63;
  const int w = tid >> 6;
  const int wm = (w & 1) * 64;
  const int wn = (w >> 1) * 64;
  const int quad = lane >> 4;
  const int r16 = lane & 15;

  f32x4 acc[4][4];
#pragma unroll
  for (int i = 0; i < 4; ++i)
#pragma unroll
    for (int j = 0; j < 4; ++j)
      acc[i][j] = (f32x4){0.f, 0.f, 0.f, 0.f};

  const int c0 = w * 2;
  for (int kt = 0; kt < 16; ++kt) {
    __syncthreads();
    const int kbase = kt * 32;
#pragma unroll
    for (int c = 0; c < 2; ++c) {
      int chunk = c0 + c;
      int mrow = chunk * 16 + (lane >> 2);
      int kk = kbase + (lane & 3) * 8;
      int gm = m0 + mrow; if (gm > M - 1) gm = M - 1;  // clamp: garbage rows masked at store
      __builtin_amdgcn_global_load_lds(
          (__attribute__((address_space(1))) void*)(void*)(Z + (size_t)gm * D + kk),
          (__attribute__((address_space(3))) void*)(As + chunk * 512),
          16, 0, 0);
      int nrow = n0 + mrow;
      __builtin_amdgcn_global_load_lds(
          (__attribute__((address_space(1))) void*)(void*)(Wt + (size_t)nrow * D + kk),
          (__attribute__((address_space(3))) void*)(Bs + chunk * 512),
          16, 0, 0);
    }
    __syncthreads();  // drains vmcnt before use

    bf16x8 a[4], b[4];
#pragma unroll
    for (int i = 0; i < 4; ++i) {
      a[i] = *(const bf16x8*)&As[(wm + i * 16 + r16) * 32 + quad * 8];
      b[i] = *(const bf16x8*)&Bs[(wn + i * 16 + r16) * 32 + quad * 8];
    }
#pragma unroll
    for (int i = 0; i < 4; ++i)
#pragma unroll
      for (int j = 0; j < 4; ++j)
        acc[i][j] = __builtin_amdgcn_mfma_f32_16x16x32_bf16(a[i], b[j], acc[i][j], 0, 0, 0);
  }

  // epilogue: C/D map col=lane&15, row=quad*4+reg
#pragma unroll
  for (int j = 0; j < 4; ++j) {
    int gn = n0 + wn + j * 16 + r16;
    float bv = bias[gn];
#pragma unroll
    for (int i = 0; i < 4; ++i) {
      int gmb = m0 + wm + i * 16 + quad * 4;
#pragma unroll
      for (int r = 0; r < 4; ++r) {
        int gm = gmb + r;
        if (gm < M) {
          float vv = acc[i][j][r] + bv;
          vv = vv > 0.f ? vv : 0.f;
          Hout[(size_t)gm * D + gn] = f2bf(vv);
        }
      }
    }
  }
}

// ---------------- classifier: out = h3 @ Wc + bc (fp32) ----------------
__global__ __launch_bounds__(256) void cls_kernel(const unsigned short* __restrict__ hb,
    const float* __restrict__ Wc, const float* __restrict__ bc, float* __restrict__ out) {
  __shared__ float hrow[4][D];
  int w = threadIdx.x >> 6, lane = threadIdx.x & 63;
  int node = blockIdx.x * 4 + w;  // grid is exactly N_NODES/4, no guard needed
  ushort8v v = *(const ushort8v*)&hb[(size_t)node * D + lane * 8];
#pragma unroll
  for (int t = 0; t < 8; ++t) hrow[w][lane * 8 + t] = bf2f(v[t]);
  __syncthreads();
  if (lane < NCLS) {
    float acc = bc[lane];
#pragma unroll 8
    for (int k = 0; k < D; ++k)
      acc += hrow[w][k] * Wc[k * NCLS + lane];
    out[(size_t)node * NCLS + lane] = acc;
  }
}

extern "C" void kernel_launch(void* const* d_in, const int* in_sizes, int n_in,
                              void* d_out, int out_size, void* d_ws, size_t ws_size,
                              hipStream_t stream) {
  const float* feat = (const float*)d_in[0];
  const int* src = (const int*)d_in[1];
  const int* dst = (const int*)d_in[2];
  const float* W0 = (const float*)d_in[3];
  const float* b0 = (const float*)d_in[4];
  const float* W1 = (const float*)d_in[5];
  const float* b1 = (const float*)d_in[6];
  const float* W2 = (const float*)d_in[7];
  const float* b2 = (const float*)d_in[8];
  const float* Wc = (const float*)d_in[9];
  const float* bc = (const float*)d_in[10];
  float* out = (float*)d_out;

  char* ws = (char*)d_ws;
  size_t off = 0;
  auto alloc = [&](size_t bytes) {
    char* p = ws + off;
    off += (bytes + 255) & ~(size_t)255;
    return p;
  };
  unsigned short* hb = (unsigned short*)alloc((size_t)N_NODES * D * 2);   // 51.2 MB
  unsigned short* zb = (unsigned short*)alloc((size_t)N_NODES * D * 2);   // 51.2 MB
  unsigned short* Wt = (unsigned short*)alloc((size_t)3 * D * D * 2);     // 1.5 MB
  int* row_ptr = (int*)alloc((size_t)(N_NODES + 1) * 4);
  int* counts  = (int*)alloc((size_t)N_NODES * 4);
  int* cursor  = (int*)alloc((size_t)N_NODES * 4);
  int* esrc    = (int*)alloc((size_t)N_EDGES * 4);

  // CSR build (graph static per launch; reused for all 3 layers)
  hipMemsetAsync(counts, 0, (size_t)N_NODES * 4, stream);
  hist_kernel<<<(N_EDGES + 255) / 256, 256, 0, stream>>>(dst, counts);
  scan_kernel<<<1, 1024, 0, stream>>>(counts, row_ptr, cursor);
  fill_kernel<<<(N_EDGES + 255) / 256, 256, 0, stream>>>(src, dst, cursor, esrc);

  cvt_feat_kernel<<<(N_NODES * D / 4 + 255) / 256, 256, 0, stream>>>(feat, hb);
  cvt_w_kernel<<<1024, 256, 0, stream>>>(W0, Wt);
  cvt_w_kernel<<<1024, 256, 0, stream>>>(W1, Wt + (size_t)D * D);
  cvt_w_kernel<<<1024, 256, 0, stream>>>(W2, Wt + (size_t)2 * D * D);

  dim3 ggrid((N_NODES + 127) / 128, 4);
  const float* bs[3] = {b0, b1, b2};
  for (int l = 0; l < 3; ++l) {
    agg_kernel<<<N_NODES / 4, 256, 0, stream>>>(hb, row_ptr, esrc, zb);
    gemm_kernel<<<ggrid, 256, 0, stream>>>(zb, Wt + (size_t)l * D * D, bs[l], hb, N_NODES);
  }
  cls_kernel<<<N_NODES / 4, 256, 0, stream>>>(hb, Wc, bc, out);
}

// Round 2
// 768.276 us; speedup vs baseline: 1.1961x; 1.1961x over previous
//
#include <hip/hip_runtime.h>

#define N_NODES 50000
#define N_EDGES 400000
#define D 512
#define NCLS 40

typedef __attribute__((ext_vector_type(8))) __bf16 bf16x8;
typedef __attribute__((ext_vector_type(4))) float f32x4;
typedef __attribute__((ext_vector_type(4))) float float4v;
typedef __attribute__((ext_vector_type(8))) unsigned short ushort8v;
typedef __attribute__((ext_vector_type(4))) unsigned short ushort4v;

__device__ __forceinline__ float bf2f(unsigned short u) {
  union { unsigned int i; float f; } v; v.i = ((unsigned int)u) << 16; return v.f;
}
__device__ __forceinline__ unsigned short f2bf(float f) {
  union { float f; unsigned int i; } v; v.f = f;
  unsigned int u = v.i;
  u += 0x7fffu + ((u >> 16) & 1u);  // round-nearest-even
  return (unsigned short)(u >> 16);
}

// ---------------- CSR build ----------------
__global__ void hist_kernel(const int* __restrict__ dst, int* __restrict__ counts) {
  int e = blockIdx.x * blockDim.x + threadIdx.x;
  if (e < N_EDGES) atomicAdd(&counts[dst[e]], 1);
}

__global__ void scan_kernel(const int* __restrict__ counts, int* __restrict__ row_ptr,
                            int* __restrict__ cursor) {
  __shared__ int sdata[1024];
  __shared__ int carry;
  if (threadIdx.x == 0) { carry = 0; row_ptr[0] = 0; }
  __syncthreads();
  for (int base = 0; base < N_NODES; base += 1024) {
    int i = base + threadIdx.x;
    int v = (i < N_NODES) ? counts[i] : 0;
    sdata[threadIdx.x] = v;
    __syncthreads();
    for (int offt = 1; offt < 1024; offt <<= 1) {
      int t = (threadIdx.x >= offt) ? sdata[threadIdx.x - offt] : 0;
      __syncthreads();
      sdata[threadIdx.x] += t;
      __syncthreads();
    }
    if (i < N_NODES) {
      int incl = sdata[threadIdx.x];
      row_ptr[i + 1] = carry + incl;
      cursor[i] = carry + incl - v;  // exclusive prefix
    }
    __syncthreads();
    if (threadIdx.x == 1023) carry += sdata[1023];
    __syncthreads();
  }
}

__global__ void fill_kernel(const int* __restrict__ src, const int* __restrict__ dst,
                            int* __restrict__ cursor, int* __restrict__ esrc) {
  int e = blockIdx.x * blockDim.x + threadIdx.x;
  if (e < N_EDGES) {
    int pos = atomicAdd(&cursor[dst[e]], 1);
    esrc[pos] = src[e];
  }
}

// ---------------- conversions ----------------
__global__ void cvt_feat_kernel(const float* __restrict__ feat, unsigned short* __restrict__ hb) {
  size_t i = (size_t)(blockIdx.x * blockDim.x + threadIdx.x) * 4;
  if (i < (size_t)N_NODES * D) {
    float4v v = *(const float4v*)&feat[i];
    ushort4v o;
    o[0] = f2bf(v[0]); o[1] = f2bf(v[1]); o[2] = f2bf(v[2]); o[3] = f2bf(v[3]);
    *(ushort4v*)&hb[i] = o;
  }
}

// Wt[n*512 + k] = bf16(W[k*512 + n])   (transpose so GEMM B-frag reads are contiguous in k)
__global__ void cvt_w_kernel(const float* __restrict__ W, unsigned short* __restrict__ Wt) {
  int i = blockIdx.x * blockDim.x + threadIdx.x;
  int n = i >> 9, k = i & 511;
  Wt[i] = f2bf(W[k * D + n]);
}

// Wct[n*512 + k] = bf16(Wc[k*40 + n]) for n<40, else 0.  [48][512] bf16, 49 KB.
__global__ void cvt_wc_kernel(const float* __restrict__ Wc, unsigned short* __restrict__ Wct) {
  int i = blockIdx.x * blockDim.x + threadIdx.x;
  if (i < 48 * D) {
    int n = i >> 9, k = i & 511;
    Wct[i] = (n < NCLS) ? f2bf(Wc[k * NCLS + n]) : (unsigned short)0;
  }
}

// ---------------- aggregation: z = h + sum_{e: dst=i} h[src[e]] ----------------
__global__ __launch_bounds__(256) void agg_kernel(const unsigned short* __restrict__ hb,
    const int* __restrict__ row_ptr, const int* __restrict__ esrc,
    unsigned short* __restrict__ zb) {
  int w = threadIdx.x >> 6, lane = threadIdx.x & 63;
  int node = blockIdx.x * 4 + w;
  int col = lane * 8;
  float acc[8];
  ushort8v v = *(const ushort8v*)&hb[(size_t)node * D + col];
#pragma unroll
  for (int t = 0; t < 8; ++t) acc[t] = bf2f(v[t]);
  int s = row_ptr[node], e = row_ptr[node + 1];
  for (int j = s; j < e; ++j) {
    int sn = esrc[j];
    ushort8v nv = *(const ushort8v*)&hb[(size_t)sn * D + col];
#pragma unroll
    for (int t = 0; t < 8; ++t) acc[t] += bf2f(nv[t]);
  }
  ushort8v o;
#pragma unroll
  for (int t = 0; t < 8; ++t) o[t] = f2bf(acc[t]);
  *(ushort8v*)&zb[(size_t)node * D + col] = o;
}

// ---------------- GEMM: Hout = relu(Z @ W + b), bf16 MFMA, m97 structure ----------------
__global__ __launch_bounds__(256) void gemm_kernel(
    const unsigned short* __restrict__ Z, const unsigned short* __restrict__ Wt,
    const float* __restrict__ bias, unsigned short* __restrict__ Hout, int M) {
  __shared__ unsigned short As[128 * 32];
  __shared__ unsigned short Bs[128 * 32];
  const int m0 = blockIdx.x * 128;
  const int n0 = blockIdx.y * 128;
  const int tid = threadIdx.x;
  const int lane = tid & 63;
  const int w = tid >> 6;
  const int wm = (w & 1) * 64;
  const int wn = (w >> 1) * 64;
  const int quad = lane >> 4;
  const int r16 = lane & 15;

  f32x4 acc[4][4];
#pragma unroll
  for (int i = 0; i < 4; ++i)
#pragma unroll
    for (int j = 0; j < 4; ++j)
      acc[i][j] = (f32x4){0.f, 0.f, 0.f, 0.f};

  const int c0 = w * 2;
  for (int kt = 0; kt < 16; ++kt) {
    __syncthreads();
    const int kbase = kt * 32;
#pragma unroll
    for (int c = 0; c < 2; ++c) {
      int chunk = c0 + c;
      int mrow = chunk * 16 + (lane >> 2);
      int kk = kbase + (lane & 3) * 8;
      int gm = m0 + mrow; if (gm > M - 1) gm = M - 1;  // clamp: garbage rows masked at store
      __builtin_amdgcn_global_load_lds(
          (__attribute__((address_space(1))) void*)(void*)(Z + (size_t)gm * D + kk),
          (__attribute__((address_space(3))) void*)(As + chunk * 512),
          16, 0, 0);
      int nrow = n0 + mrow;
      __builtin_amdgcn_global_load_lds(
          (__attribute__((address_space(1))) void*)(void*)(Wt + (size_t)nrow * D + kk),
          (__attribute__((address_space(3))) void*)(Bs + chunk * 512),
          16, 0, 0);
    }
    __syncthreads();  // drains vmcnt before use

    bf16x8 a[4], b[4];
#pragma unroll
    for (int i = 0; i < 4; ++i) {
      a[i] = *(const bf16x8*)&As[(wm + i * 16 + r16) * 32 + quad * 8];
      b[i] = *(const bf16x8*)&Bs[(wn + i * 16 + r16) * 32 + quad * 8];
    }
#pragma unroll
    for (int i = 0; i < 4; ++i)
#pragma unroll
      for (int j = 0; j < 4; ++j)
        acc[i][j] = __builtin_amdgcn_mfma_f32_16x16x32_bf16(a[i], b[j], acc[i][j], 0, 0, 0);
  }

  // epilogue: C/D map col=lane&15, row=quad*4+reg
#pragma unroll
  for (int j = 0; j < 4; ++j) {
    int gn = n0 + wn + j * 16 + r16;
    float bv = bias[gn];
#pragma unroll
    for (int i = 0; i < 4; ++i) {
      int gmb = m0 + wm + i * 16 + quad * 4;
#pragma unroll
      for (int r = 0; r < 4; ++r) {
        int gm = gmb + r;
        if (gm < M) {
          float vv = acc[i][j][r] + bv;
          vv = vv > 0.f ? vv : 0.f;
          Hout[(size_t)gm * D + gn] = f2bf(vv);
        }
      }
    }
  }
}

// ---------------- classifier: out = h3 @ Wc + bc  (bf16 MFMA, no LDS) ----------------
// One wave = 16 rows (1 m-frag), 3 n-frags (N padded 40->48). A-frags straight from
// global (16 rows x 64B contiguous per ktile, each byte read once); B-frags from the
// 48 KB L1/L2-resident Wct. No syncthreads, no LDS.
__global__ __launch_bounds__(256) void cls_kernel(const unsigned short* __restrict__ hb,
    const unsigned short* __restrict__ Wct, const float* __restrict__ bc,
    float* __restrict__ out) {
  int w = threadIdx.x >> 6, lane = threadIdx.x & 63;
  int quad = lane >> 4, r16 = lane & 15;
  int nb = blockIdx.x * 64 + w * 16;
  int arow = nb + r16; if (arow > N_NODES - 1) arow = N_NODES - 1;
  f32x4 acc[3];
#pragma unroll
  for (int j = 0; j < 3; ++j) acc[j] = (f32x4){0.f, 0.f, 0.f, 0.f};
#pragma unroll 4
  for (int kt = 0; kt < 16; ++kt) {
    int kk = kt * 32 + quad * 8;
    bf16x8 a = *(const bf16x8*)&hb[(size_t)arow * D + kk];
#pragma unroll
    for (int j = 0; j < 3; ++j) {
      bf16x8 b = *(const bf16x8*)&Wct[(size_t)(j * 16 + r16) * D + kk];
      acc[j] = __builtin_amdgcn_mfma_f32_16x16x32_bf16(a, b, acc[j], 0, 0, 0);
    }
  }
  // C/D: col(n)=r16, row(m)=quad*4+reg
#pragma unroll
  for (int j = 0; j < 3; ++j) {
    int gn = j * 16 + r16;
    if (gn < NCLS) {
      float bv = bc[gn];
#pragma unroll
      for (int r = 0; r < 4; ++r) {
        int gm = nb + quad * 4 + r;
        if (gm < N_NODES) out[(size_t)gm * NCLS + gn] = acc[j][r] + bv;
      }
    }
  }
}

extern "C" void kernel_launch(void* const* d_in, const int* in_sizes, int n_in,
                              void* d_out, int out_size, void* d_ws, size_t ws_size,
                              hipStream_t stream) {
  const float* feat = (const float*)d_in[0];
  const int* src = (const int*)d_in[1];
  const int* dst = (const int*)d_in[2];
  const float* W0 = (const float*)d_in[3];
  const float* b0 = (const float*)d_in[4];
  const float* W1 = (const float*)d_in[5];
  const float* b1 = (const float*)d_in[6];
  const float* W2 = (const float*)d_in[7];
  const float* b2 = (const float*)d_in[8];
  const float* Wc = (const float*)d_in[9];
  const float* bc = (const float*)d_in[10];
  float* out = (float*)d_out;

  char* ws = (char*)d_ws;
  size_t off = 0;
  auto alloc = [&](size_t bytes) {
    char* p = ws + off;
    off += (bytes + 255) & ~(size_t)255;
    return p;
  };
  unsigned short* hb = (unsigned short*)alloc((size_t)N_NODES * D * 2);   // 51.2 MB
  unsigned short* zb = (unsigned short*)alloc((size_t)N_NODES * D * 2);   // 51.2 MB
  unsigned short* Wt = (unsigned short*)alloc((size_t)3 * D * D * 2);     // 1.5 MB
  unsigned short* Wct = (unsigned short*)alloc((size_t)48 * D * 2);       // 49 KB
  int* row_ptr = (int*)alloc((size_t)(N_NODES + 1) * 4);
  int* counts  = (int*)alloc((size_t)N_NODES * 4);
  int* cursor  = (int*)alloc((size_t)N_NODES * 4);
  int* esrc    = (int*)alloc((size_t)N_EDGES * 4);

  // CSR build (graph static per launch; reused for all 3 layers)
  hipMemsetAsync(counts, 0, (size_t)N_NODES * 4, stream);
  hist_kernel<<<(N_EDGES + 255) / 256, 256, 0, stream>>>(dst, counts);
  scan_kernel<<<1, 1024, 0, stream>>>(counts, row_ptr, cursor);
  fill_kernel<<<(N_EDGES + 255) / 256, 256, 0, stream>>>(src, dst, cursor, esrc);

  cvt_feat_kernel<<<(N_NODES * D / 4 + 255) / 256, 256, 0, stream>>>(feat, hb);
  cvt_w_kernel<<<1024, 256, 0, stream>>>(W0, Wt);
  cvt_w_kernel<<<1024, 256, 0, stream>>>(W1, Wt + (size_t)D * D);
  cvt_w_kernel<<<1024, 256, 0, stream>>>(W2, Wt + (size_t)2 * D * D);
  cvt_wc_kernel<<<(48 * D + 255) / 256, 256, 0, stream>>>(Wc, Wct);

  dim3 ggrid((N_NODES + 127) / 128, 4);
  const float* bs[3] = {b0, b1, b2};
  for (int l = 0; l < 3; ++l) {
    agg_kernel<<<N_NODES / 4, 256, 0, stream>>>(hb, row_ptr, esrc, zb);
    gemm_kernel<<<ggrid, 256, 0, stream>>>(zb, Wt + (size_t)l * D * D, bs[l], hb, N_NODES);
  }
  cls_kernel<<<(N_NODES + 63) / 64, 256, 0, stream>>>(hb, Wct, bc, out);
}

// Round 3
// 684.752 us; speedup vs baseline: 1.3420x; 1.1220x over previous
//
#include <hip/hip_runtime.h>

#define N_NODES 50000
#define N_EDGES 400000
#define D 512
#define NCLS 40
#define SCAN_BLOCKS ((N_NODES + 255) / 256)

typedef __attribute__((ext_vector_type(8))) __bf16 bf16x8;
typedef __attribute__((ext_vector_type(4))) float f32x4;
typedef __attribute__((ext_vector_type(4))) float float4v;
typedef __attribute__((ext_vector_type(8))) unsigned short ushort8v;
typedef __attribute__((ext_vector_type(4))) unsigned short ushort4v;

__device__ __forceinline__ float bf2f(unsigned short u) {
  union { unsigned int i; float f; } v; v.i = ((unsigned int)u) << 16; return v.f;
}
__device__ __forceinline__ unsigned short f2bf(float f) {
  union { float f; unsigned int i; } v; v.f = f;
  unsigned int u = v.i;
  u += 0x7fffu + ((u >> 16) & 1u);  // round-nearest-even
  return (unsigned short)(u >> 16);
}

// ---------------- CSR build ----------------
__global__ void hist_kernel(const int* __restrict__ dst, int* __restrict__ counts) {
  int e = blockIdx.x * blockDim.x + threadIdx.x;
  if (e < N_EDGES) atomicAdd(&counts[dst[e]], 1);
}

// Phase 1: per-block inclusive scan (256 elems/block); incl -> cursor buf, block sum -> bsum
__global__ __launch_bounds__(256) void scan_local_kernel(const int* __restrict__ counts,
    int* __restrict__ incl, int* __restrict__ bsum) {
  __shared__ int s[256];
  int i = blockIdx.x * 256 + threadIdx.x;
  int v = (i < N_NODES) ? counts[i] : 0;
  s[threadIdx.x] = v;
  __syncthreads();
#pragma unroll
  for (int o = 1; o < 256; o <<= 1) {
    int t = (threadIdx.x >= o) ? s[threadIdx.x - o] : 0;
    __syncthreads();
    s[threadIdx.x] += t;
    __syncthreads();
  }
  if (i < N_NODES) incl[i] = s[threadIdx.x];
  if (threadIdx.x == 255) bsum[blockIdx.x] = s[255];
}

// Phase 2: single tiny block scans the block sums -> exclusive block offsets (in place)
__global__ __launch_bounds__(256) void scan_bsum_kernel(int* __restrict__ bsum) {
  __shared__ int s[256];
  int v = (threadIdx.x < SCAN_BLOCKS) ? bsum[threadIdx.x] : 0;
  s[threadIdx.x] = v;
  __syncthreads();
#pragma unroll
  for (int o = 1; o < 256; o <<= 1) {
    int t = (threadIdx.x >= o) ? s[threadIdx.x - o] : 0;
    __syncthreads();
    s[threadIdx.x] += t;
    __syncthreads();
  }
  if (threadIdx.x < SCAN_BLOCKS) bsum[threadIdx.x] = s[threadIdx.x] - v;  // exclusive
}

// Phase 3: add block offsets; emit row_ptr and cursor (cursor buf doubled as incl)
__global__ __launch_bounds__(256) void scan_finish_kernel(const int* __restrict__ counts,
    const int* __restrict__ bsum, int* __restrict__ row_ptr, int* __restrict__ cursor) {
  int i = blockIdx.x * 256 + threadIdx.x;
  if (i < N_NODES) {
    int inc = cursor[i] + bsum[blockIdx.x];
    row_ptr[i + 1] = inc;
    cursor[i] = inc - counts[i];  // exclusive prefix = fill start
    if (i == 0) row_ptr[0] = 0;
  }
}

__global__ void fill_kernel(const int* __restrict__ src, const int* __restrict__ dst,
                            int* __restrict__ cursor, int* __restrict__ esrc) {
  int e = blockIdx.x * blockDim.x + threadIdx.x;
  if (e < N_EDGES) {
    int pos = atomicAdd(&cursor[dst[e]], 1);
    esrc[pos] = src[e];
  }
}

// ---------------- conversions ----------------
__global__ void cvt_feat_kernel(const float* __restrict__ feat, unsigned short* __restrict__ hb) {
  size_t i = (size_t)(blockIdx.x * blockDim.x + threadIdx.x) * 4;
  if (i < (size_t)N_NODES * D) {
    float4v v = *(const float4v*)&feat[i];
    ushort4v o;
    o[0] = f2bf(v[0]); o[1] = f2bf(v[1]); o[2] = f2bf(v[2]); o[3] = f2bf(v[3]);
    *(ushort4v*)&hb[i] = o;
  }
}

// Wt[n*512 + k] = bf16(W[k*512 + n])
__global__ void cvt_w_kernel(const float* __restrict__ W, unsigned short* __restrict__ Wt) {
  int i = blockIdx.x * blockDim.x + threadIdx.x;
  int n = i >> 9, k = i & 511;
  Wt[i] = f2bf(W[k * D + n]);
}

// Wct[n*512 + k] = bf16(Wc[k*40 + n]) for n<40, else 0.  [48][512] bf16, 49 KB.
__global__ void cvt_wc_kernel(const float* __restrict__ Wc, unsigned short* __restrict__ Wct) {
  int i = blockIdx.x * blockDim.x + threadIdx.x;
  if (i < 48 * D) {
    int n = i >> 9, k = i & 511;
    Wct[i] = (n < NCLS) ? f2bf(Wc[k * NCLS + n]) : (unsigned short)0;
  }
}

// ---------------- aggregation: z = h + sum_{e: dst=i} h[src[e]] ----------------
__global__ __launch_bounds__(256) void agg_kernel(const unsigned short* __restrict__ hb,
    const int* __restrict__ row_ptr, const int* __restrict__ esrc,
    unsigned short* __restrict__ zb) {
  int w = threadIdx.x >> 6, lane = threadIdx.x & 63;
  int node = blockIdx.x * 4 + w;
  int col = lane * 8;
  float acc[8];
  ushort8v v = *(const ushort8v*)&hb[(size_t)node * D + col];
#pragma unroll
  for (int t = 0; t < 8; ++t) acc[t] = bf2f(v[t]);
  int s = row_ptr[node], e = row_ptr[node + 1];
  for (int j = s; j < e; ++j) {
    int sn = esrc[j];
    ushort8v nv = *(const ushort8v*)&hb[(size_t)sn * D + col];
#pragma unroll
    for (int t = 0; t < 8; ++t) acc[t] += bf2f(nv[t]);
  }
  ushort8v o;
#pragma unroll
  for (int t = 0; t < 8; ++t) o[t] = f2bf(acc[t]);
  *(ushort8v*)&zb[(size_t)node * D + col] = o;
}

// ---------------- GEMM: Hout = relu(Z @ W + b), bf16 MFMA, m97 structure ----------------
__global__ __launch_bounds__(256) void gemm_kernel(
    const unsigned short* __restrict__ Z, const unsigned short* __restrict__ Wt,
    const float* __restrict__ bias, unsigned short* __restrict__ Hout, int M) {
  __shared__ unsigned short As[128 * 32];
  __shared__ unsigned short Bs[128 * 32];
  const int m0 = blockIdx.x * 128;
  const int n0 = blockIdx.y * 128;
  const int tid = threadIdx.x;
  const int lane = tid & 63;
  const int w = tid >> 6;
  const int wm = (w & 1) * 64;
  const int wn = (w >> 1) * 64;
  const int quad = lane >> 4;
  const int r16 = lane & 15;

  f32x4 acc[4][4];
#pragma unroll
  for (int i = 0; i < 4; ++i)
#pragma unroll
    for (int j = 0; j < 4; ++j)
      acc[i][j] = (f32x4){0.f, 0.f, 0.f, 0.f};

  const int c0 = w * 2;
  for (int kt = 0; kt < 16; ++kt) {
    __syncthreads();
    const int kbase = kt * 32;
#pragma unroll
    for (int c = 0; c < 2; ++c) {
      int chunk = c0 + c;
      int mrow = chunk * 16 + (lane >> 2);
      int kk = kbase + (lane & 3) * 8;
      int gm = m0 + mrow; if (gm > M - 1) gm = M - 1;  // clamp: garbage rows masked at store
      __builtin_amdgcn_global_load_lds(
          (__attribute__((address_space(1))) void*)(void*)(Z + (size_t)gm * D + kk),
          (__attribute__((address_space(3))) void*)(As + chunk * 512),
          16, 0, 0);
      int nrow = n0 + mrow;
      __builtin_amdgcn_global_load_lds(
          (__attribute__((address_space(1))) void*)(void*)(Wt + (size_t)nrow * D + kk),
          (__attribute__((address_space(3))) void*)(Bs + chunk * 512),
          16, 0, 0);
    }
    __syncthreads();  // drains vmcnt before use

    bf16x8 a[4], b[4];
#pragma unroll
    for (int i = 0; i < 4; ++i) {
      a[i] = *(const bf16x8*)&As[(wm + i * 16 + r16) * 32 + quad * 8];
      b[i] = *(const bf16x8*)&Bs[(wn + i * 16 + r16) * 32 + quad * 8];
    }
#pragma unroll
    for (int i = 0; i < 4; ++i)
#pragma unroll
      for (int j = 0; j < 4; ++j)
        acc[i][j] = __builtin_amdgcn_mfma_f32_16x16x32_bf16(a[i], b[j], acc[i][j], 0, 0, 0);
  }

  // epilogue: C/D map col=lane&15, row=quad*4+reg
#pragma unroll
  for (int j = 0; j < 4; ++j) {
    int gn = n0 + wn + j * 16 + r16;
    float bv = bias[gn];
#pragma unroll
    for (int i = 0; i < 4; ++i) {
      int gmb = m0 + wm + i * 16 + quad * 4;
#pragma unroll
      for (int r = 0; r < 4; ++r) {
        int gm = gmb + r;
        if (gm < M) {
          float vv = acc[i][j][r] + bv;
          vv = vv > 0.f ? vv : 0.f;
          Hout[(size_t)gm * D + gn] = f2bf(vv);
        }
      }
    }
  }
}

// ---------------- classifier: out = h3 @ Wc + bc  (bf16 MFMA, no LDS) ----------------
__global__ __launch_bounds__(256) void cls_kernel(const unsigned short* __restrict__ hb,
    const unsigned short* __restrict__ Wct, const float* __restrict__ bc,
    float* __restrict__ out) {
  int w = threadIdx.x >> 6, lane = threadIdx.x & 63;
  int quad = lane >> 4, r16 = lane & 15;
  int nb = blockIdx.x * 64 + w * 16;
  int arow = nb + r16; if (arow > N_NODES - 1) arow = N_NODES - 1;
  f32x4 acc[3];
#pragma unroll
  for (int j = 0; j < 3; ++j) acc[j] = (f32x4){0.f, 0.f, 0.f, 0.f};
#pragma unroll 4
  for (int kt = 0; kt < 16; ++kt) {
    int kk = kt * 32 + quad * 8;
    bf16x8 a = *(const bf16x8*)&hb[(size_t)arow * D + kk];
#pragma unroll
    for (int j = 0; j < 3; ++j) {
      bf16x8 b = *(const bf16x8*)&Wct[(size_t)(j * 16 + r16) * D + kk];
      acc[j] = __builtin_amdgcn_mfma_f32_16x16x32_bf16(a, b, acc[j], 0, 0, 0);
    }
  }
  // C/D: col(n)=r16, row(m)=quad*4+reg
#pragma unroll
  for (int j = 0; j < 3; ++j) {
    int gn = j * 16 + r16;
    if (gn < NCLS) {
      float bv = bc[gn];
#pragma unroll
      for (int r = 0; r < 4; ++r) {
        int gm = nb + quad * 4 + r;
        if (gm < N_NODES) out[(size_t)gm * NCLS + gn] = acc[j][r] + bv;
      }
    }
  }
}

extern "C" void kernel_launch(void* const* d_in, const int* in_sizes, int n_in,
                              void* d_out, int out_size, void* d_ws, size_t ws_size,
                              hipStream_t stream) {
  const float* feat = (const float*)d_in[0];
  const int* src = (const int*)d_in[1];
  const int* dst = (const int*)d_in[2];
  const float* W0 = (const float*)d_in[3];
  const float* b0 = (const float*)d_in[4];
  const float* W1 = (const float*)d_in[5];
  const float* b1 = (const float*)d_in[6];
  const float* W2 = (const float*)d_in[7];
  const float* b2 = (const float*)d_in[8];
  const float* Wc = (const float*)d_in[9];
  const float* bc = (const float*)d_in[10];
  float* out = (float*)d_out;

  char* ws = (char*)d_ws;
  size_t off = 0;
  auto alloc = [&](size_t bytes) {
    char* p = ws + off;
    off += (bytes + 255) & ~(size_t)255;
    return p;
  };
  unsigned short* hb = (unsigned short*)alloc((size_t)N_NODES * D * 2);   // 51.2 MB
  unsigned short* zb = (unsigned short*)alloc((size_t)N_NODES * D * 2);   // 51.2 MB
  unsigned short* Wt = (unsigned short*)alloc((size_t)3 * D * D * 2);     // 1.5 MB
  unsigned short* Wct = (unsigned short*)alloc((size_t)48 * D * 2);       // 49 KB
  int* row_ptr = (int*)alloc((size_t)(N_NODES + 1) * 4);
  int* counts  = (int*)alloc((size_t)N_NODES * 4);
  int* cursor  = (int*)alloc((size_t)N_NODES * 4);   // doubles as incl-scan buffer
  int* esrc    = (int*)alloc((size_t)N_EDGES * 4);
  int* bsum    = (int*)alloc((size_t)256 * 4);

  // CSR build (graph static per launch; reused for all 3 layers)
  hipMemsetAsync(counts, 0, (size_t)N_NODES * 4, stream);
  hist_kernel<<<(N_EDGES + 255) / 256, 256, 0, stream>>>(dst, counts);
  scan_local_kernel<<<SCAN_BLOCKS, 256, 0, stream>>>(counts, cursor, bsum);
  scan_bsum_kernel<<<1, 256, 0, stream>>>(bsum);
  scan_finish_kernel<<<SCAN_BLOCKS, 256, 0, stream>>>(counts, bsum, row_ptr, cursor);
  fill_kernel<<<(N_EDGES + 255) / 256, 256, 0, stream>>>(src, dst, cursor, esrc);

  cvt_feat_kernel<<<(N_NODES * D / 4 + 255) / 256, 256, 0, stream>>>(feat, hb);
  cvt_w_kernel<<<1024, 256, 0, stream>>>(W0, Wt);
  cvt_w_kernel<<<1024, 256, 0, stream>>>(W1, Wt + (size_t)D * D);
  cvt_w_kernel<<<1024, 256, 0, stream>>>(W2, Wt + (size_t)2 * D * D);
  cvt_wc_kernel<<<(48 * D + 255) / 256, 256, 0, stream>>>(Wc, Wct);

  dim3 ggrid((N_NODES + 127) / 128, 4);
  const float* bs[3] = {b0, b1, b2};
  for (int l = 0; l < 3; ++l) {
    agg_kernel<<<N_NODES / 4, 256, 0, stream>>>(hb, row_ptr, esrc, zb);
    gemm_kernel<<<ggrid, 256, 0, stream>>>(zb, Wt + (size_t)l * D * D, bs[l], hb, N_NODES);
  }
  cls_kernel<<<(N_NODES + 63) / 64, 256, 0, stream>>>(hb, Wct, bc, out);
}

// Round 4
// 626.548 us; speedup vs baseline: 1.4667x; 1.0929x over previous
//
#include <hip/hip_runtime.h>

#define N_NODES 50000
#define N_EDGES 400000
#define D 512
#define NCLS 40
#define SCAN_BLOCKS ((N_NODES + 255) / 256)

typedef __attribute__((ext_vector_type(8))) __bf16 bf16x8;
typedef __attribute__((ext_vector_type(4))) float f32x4;
typedef __attribute__((ext_vector_type(4))) float float4v;
typedef __attribute__((ext_vector_type(8))) unsigned short ushort8v;
typedef __attribute__((ext_vector_type(4))) unsigned short ushort4v;

__device__ __forceinline__ float bf2f(unsigned short u) {
  union { unsigned int i; float f; } v; v.i = ((unsigned int)u) << 16; return v.f;
}
__device__ __forceinline__ unsigned short f2bf(float f) {
  union { float f; unsigned int i; } v; v.f = f;
  unsigned int u = v.i;
  u += 0x7fffu + ((u >> 16) & 1u);  // round-nearest-even
  return (unsigned short)(u >> 16);
}

// ---------------- CSR build ----------------
__global__ void hist_kernel(const int* __restrict__ dst, int* __restrict__ counts) {
  int e = blockIdx.x * blockDim.x + threadIdx.x;
  if (e < N_EDGES) atomicAdd(&counts[dst[e]], 1);
}

// Phase 1: per-block inclusive scan (256 elems/block); incl -> cursor buf, block sum -> bsum
__global__ __launch_bounds__(256) void scan_local_kernel(const int* __restrict__ counts,
    int* __restrict__ incl, int* __restrict__ bsum) {
  __shared__ int s[256];
  int i = blockIdx.x * 256 + threadIdx.x;
  int v = (i < N_NODES) ? counts[i] : 0;
  s[threadIdx.x] = v;
  __syncthreads();
#pragma unroll
  for (int o = 1; o < 256; o <<= 1) {
    int t = (threadIdx.x >= o) ? s[threadIdx.x - o] : 0;
    __syncthreads();
    s[threadIdx.x] += t;
    __syncthreads();
  }
  if (i < N_NODES) incl[i] = s[threadIdx.x];
  if (threadIdx.x == 255) bsum[blockIdx.x] = s[255];
}

// Phase 2: single tiny block scans the block sums -> exclusive block offsets (in place)
__global__ __launch_bounds__(256) void scan_bsum_kernel(int* __restrict__ bsum) {
  __shared__ int s[256];
  int v = (threadIdx.x < SCAN_BLOCKS) ? bsum[threadIdx.x] : 0;
  s[threadIdx.x] = v;
  __syncthreads();
#pragma unroll
  for (int o = 1; o < 256; o <<= 1) {
    int t = (threadIdx.x >= o) ? s[threadIdx.x - o] : 0;
    __syncthreads();
    s[threadIdx.x] += t;
    __syncthreads();
  }
  if (threadIdx.x < SCAN_BLOCKS) bsum[threadIdx.x] = s[threadIdx.x] - v;  // exclusive
}

// Phase 3: add block offsets; emit row_ptr and cursor (cursor buf doubled as incl)
__global__ __launch_bounds__(256) void scan_finish_kernel(const int* __restrict__ counts,
    const int* __restrict__ bsum, int* __restrict__ row_ptr, int* __restrict__ cursor) {
  int i = blockIdx.x * 256 + threadIdx.x;
  if (i < N_NODES) {
    int inc = cursor[i] + bsum[blockIdx.x];
    row_ptr[i + 1] = inc;
    cursor[i] = inc - counts[i];  // exclusive prefix = fill start
    if (i == 0) row_ptr[0] = 0;
  }
}

__global__ void fill_kernel(const int* __restrict__ src, const int* __restrict__ dst,
                            int* __restrict__ cursor, int* __restrict__ esrc) {
  int e = blockIdx.x * blockDim.x + threadIdx.x;
  if (e < N_EDGES) {
    int pos = atomicAdd(&cursor[dst[e]], 1);
    esrc[pos] = src[e];
  }
}

// ---------------- conversions ----------------
__global__ void cvt_feat_kernel(const float* __restrict__ feat, unsigned short* __restrict__ hb) {
  size_t i = (size_t)(blockIdx.x * blockDim.x + threadIdx.x) * 4;
  if (i < (size_t)N_NODES * D) {
    float4v v = *(const float4v*)&feat[i];
    ushort4v o;
    o[0] = f2bf(v[0]); o[1] = f2bf(v[1]); o[2] = f2bf(v[2]); o[3] = f2bf(v[3]);
    *(ushort4v*)&hb[i] = o;
  }
}

// Wt[n*512 + k] = bf16(W[k*512 + n])
__global__ void cvt_w_kernel(const float* __restrict__ W, unsigned short* __restrict__ Wt) {
  int i = blockIdx.x * blockDim.x + threadIdx.x;
  int n = i >> 9, k = i & 511;
  Wt[i] = f2bf(W[k * D + n]);
}

// Wct[n*512 + k] = bf16(Wc[k*40 + n]) for n<40, else 0.  [48][512] bf16, 49 KB.
__global__ void cvt_wc_kernel(const float* __restrict__ Wc, unsigned short* __restrict__ Wct) {
  int i = blockIdx.x * blockDim.x + threadIdx.x;
  if (i < 48 * D) {
    int n = i >> 9, k = i & 511;
    Wct[i] = (n < NCLS) ? f2bf(Wc[k * NCLS + n]) : (unsigned short)0;
  }
}

// ---------------- aggregation: z = h + sum_{e: dst=i} h[src[e]] ----------------
__global__ __launch_bounds__(256) void agg_kernel(const unsigned short* __restrict__ hb,
    const int* __restrict__ row_ptr, const int* __restrict__ esrc,
    unsigned short* __restrict__ zb) {
  int w = threadIdx.x >> 6, lane = threadIdx.x & 63;
  int node = blockIdx.x * 4 + w;
  int col = lane * 8;
  float acc[8];
  ushort8v v = *(const ushort8v*)&hb[(size_t)node * D + col];
#pragma unroll
  for (int t = 0; t < 8; ++t) acc[t] = bf2f(v[t]);
  int s = row_ptr[node], e = row_ptr[node + 1];
  for (int j = s; j < e; ++j) {
    int sn = esrc[j];
    ushort8v nv = *(const ushort8v*)&hb[(size_t)sn * D + col];
#pragma unroll
    for (int t = 0; t < 8; ++t) acc[t] += bf2f(nv[t]);
  }
  ushort8v o;
#pragma unroll
  for (int t = 0; t < 8; ++t) o[t] = f2bf(acc[t]);
  *(ushort8v*)&zb[(size_t)node * D + col] = o;
}

// ---------------- GEMM: Hout = relu(Z @ W + b), bf16 MFMA ----------------
// 128x128 tile; grid(n_tiles=4 fastest, m_tiles). Epilogue stages C through LDS
// (stride 132 -> conflict-free b16 writes) and stores 256 B/row contiguous:
// full 64-B lines per instruction => no L2 read-modify-write, no write amplification.
__global__ __launch_bounds__(256) void gemm_kernel(
    const unsigned short* __restrict__ Z, const unsigned short* __restrict__ Wt,
    const float* __restrict__ bias, unsigned short* __restrict__ Hout, int M) {
  __shared__ unsigned short smem[128 * 132];  // 33 KB; overlays As/Bs then Cs
  unsigned short* As = smem;            // 128*32 elems
  unsigned short* Bs = smem + 4096;     // 128*32 elems
  const int n0 = blockIdx.x * 128;      // n fastest: 4 n-tiles of one m-tile adjacent
  const int m0 = blockIdx.y * 128;
  const int tid = threadIdx.x;
  const int lane = tid & 63;
  const int w = tid >> 6;
  const int wm = (w & 1) * 64;
  const int wn = (w >> 1) * 64;
  const int quad = lane >> 4;
  const int r16 = lane & 15;

  f32x4 acc[4][4];
#pragma unroll
  for (int i = 0; i < 4; ++i)
#pragma unroll
    for (int j = 0; j < 4; ++j)
      acc[i][j] = (f32x4){0.f, 0.f, 0.f, 0.f};

  const int c0 = w * 2;
  for (int kt = 0; kt < 16; ++kt) {
    __syncthreads();
    const int kbase = kt * 32;
#pragma unroll
    for (int c = 0; c < 2; ++c) {
      int chunk = c0 + c;
      int mrow = chunk * 16 + (lane >> 2);
      int kk = kbase + (lane & 3) * 8;
      int gm = m0 + mrow; if (gm > M - 1) gm = M - 1;  // clamp: garbage rows masked at store
      __builtin_amdgcn_global_load_lds(
          (__attribute__((address_space(1))) void*)(void*)(Z + (size_t)gm * D + kk),
          (__attribute__((address_space(3))) void*)(As + chunk * 512),
          16, 0, 0);
      int nrow = n0 + mrow;
      __builtin_amdgcn_global_load_lds(
          (__attribute__((address_space(1))) void*)(void*)(Wt + (size_t)nrow * D + kk),
          (__attribute__((address_space(3))) void*)(Bs + chunk * 512),
          16, 0, 0);
    }
    __syncthreads();  // drains vmcnt before use

    bf16x8 a[4], b[4];
#pragma unroll
    for (int i = 0; i < 4; ++i) {
      a[i] = *(const bf16x8*)&As[(wm + i * 16 + r16) * 32 + quad * 8];
      b[i] = *(const bf16x8*)&Bs[(wn + i * 16 + r16) * 32 + quad * 8];
    }
#pragma unroll
    for (int i = 0; i < 4; ++i)
#pragma unroll
      for (int j = 0; j < 4; ++j)
        acc[i][j] = __builtin_amdgcn_mfma_f32_16x16x32_bf16(a[i], b[j], acc[i][j], 0, 0, 0);
  }

  // ---- epilogue: bias+relu -> LDS (C tile, stride 132) -> coalesced global stores
  __syncthreads();  // all frag reads done before overwriting smem
  unsigned short* Cs = smem;
#pragma unroll
  for (int j = 0; j < 4; ++j) {
    float bv = bias[n0 + wn + j * 16 + r16];
#pragma unroll
    for (int i = 0; i < 4; ++i) {
      int crow = wm + i * 16 + quad * 4;
      int ccol = wn + j * 16 + r16;
#pragma unroll
      for (int r = 0; r < 4; ++r) {
        float vv = acc[i][j][r] + bv;
        vv = vv > 0.f ? vv : 0.f;
        Cs[(crow + r) * 132 + ccol] = f2bf(vv);
      }
    }
  }
  __syncthreads();
  // copy-out: wave w -> rows [w*32, w*32+32); per instr 4 rows x 256 B contiguous
#pragma unroll
  for (int it = 0; it < 8; ++it) {
    int row = w * 32 + it * 4 + (lane >> 4);
    int colofs = (lane & 15) * 8;
    int gm = m0 + row;
    if (gm < M) {
      ushort8v vv = *(const ushort8v*)&Cs[row * 132 + colofs];
      *(ushort8v*)&Hout[(size_t)gm * D + n0 + colofs] = vv;
    }
  }
}

// ---------------- classifier: out = h3 @ Wc + bc  (bf16 MFMA, no LDS) ----------------
__global__ __launch_bounds__(256) void cls_kernel(const unsigned short* __restrict__ hb,
    const unsigned short* __restrict__ Wct, const float* __restrict__ bc,
    float* __restrict__ out) {
  int w = threadIdx.x >> 6, lane = threadIdx.x & 63;
  int quad = lane >> 4, r16 = lane & 15;
  int nb = blockIdx.x * 64 + w * 16;
  int arow = nb + r16; if (arow > N_NODES - 1) arow = N_NODES - 1;
  f32x4 acc[3];
#pragma unroll
  for (int j = 0; j < 3; ++j) acc[j] = (f32x4){0.f, 0.f, 0.f, 0.f};
#pragma unroll 4
  for (int kt = 0; kt < 16; ++kt) {
    int kk = kt * 32 + quad * 8;
    bf16x8 a = *(const bf16x8*)&hb[(size_t)arow * D + kk];
#pragma unroll
    for (int j = 0; j < 3; ++j) {
      bf16x8 b = *(const bf16x8*)&Wct[(size_t)(j * 16 + r16) * D + kk];
      acc[j] = __builtin_amdgcn_mfma_f32_16x16x32_bf16(a, b, acc[j], 0, 0, 0);
    }
  }
  // C/D: col(n)=r16, row(m)=quad*4+reg
#pragma unroll
  for (int j = 0; j < 3; ++j) {
    int gn = j * 16 + r16;
    if (gn < NCLS) {
      float bv = bc[gn];
#pragma unroll
      for (int r = 0; r < 4; ++r) {
        int gm = nb + quad * 4 + r;
        if (gm < N_NODES) out[(size_t)gm * NCLS + gn] = acc[j][r] + bv;
      }
    }
  }
}

extern "C" void kernel_launch(void* const* d_in, const int* in_sizes, int n_in,
                              void* d_out, int out_size, void* d_ws, size_t ws_size,
                              hipStream_t stream) {
  const float* feat = (const float*)d_in[0];
  const int* src = (const int*)d_in[1];
  const int* dst = (const int*)d_in[2];
  const float* W0 = (const float*)d_in[3];
  const float* b0 = (const float*)d_in[4];
  const float* W1 = (const float*)d_in[5];
  const float* b1 = (const float*)d_in[6];
  const float* W2 = (const float*)d_in[7];
  const float* b2 = (const float*)d_in[8];
  const float* Wc = (const float*)d_in[9];
  const float* bc = (const float*)d_in[10];
  float* out = (float*)d_out;

  char* ws = (char*)d_ws;
  size_t off = 0;
  auto alloc = [&](size_t bytes) {
    char* p = ws + off;
    off += (bytes + 255) & ~(size_t)255;
    return p;
  };
  unsigned short* hb = (unsigned short*)alloc((size_t)N_NODES * D * 2);   // 51.2 MB
  unsigned short* zb = (unsigned short*)alloc((size_t)N_NODES * D * 2);   // 51.2 MB
  unsigned short* Wt = (unsigned short*)alloc((size_t)3 * D * D * 2);     // 1.5 MB
  unsigned short* Wct = (unsigned short*)alloc((size_t)48 * D * 2);       // 49 KB
  int* row_ptr = (int*)alloc((size_t)(N_NODES + 1) * 4);
  int* counts  = (int*)alloc((size_t)N_NODES * 4);
  int* cursor  = (int*)alloc((size_t)N_NODES * 4);   // doubles as incl-scan buffer
  int* esrc    = (int*)alloc((size_t)N_EDGES * 4);
  int* bsum    = (int*)alloc((size_t)256 * 4);

  // CSR build (graph static per launch; reused for all 3 layers)
  hipMemsetAsync(counts, 0, (size_t)N_NODES * 4, stream);
  hist_kernel<<<(N_EDGES + 255) / 256, 256, 0, stream>>>(dst, counts);
  scan_local_kernel<<<SCAN_BLOCKS, 256, 0, stream>>>(counts, cursor, bsum);
  scan_bsum_kernel<<<1, 256, 0, stream>>>(bsum);
  scan_finish_kernel<<<SCAN_BLOCKS, 256, 0, stream>>>(counts, bsum, row_ptr, cursor);
  fill_kernel<<<(N_EDGES + 255) / 256, 256, 0, stream>>>(src, dst, cursor, esrc);

  cvt_feat_kernel<<<(N_NODES * D / 4 + 255) / 256, 256, 0, stream>>>(feat, hb);
  cvt_w_kernel<<<1024, 256, 0, stream>>>(W0, Wt);
  cvt_w_kernel<<<1024, 256, 0, stream>>>(W1, Wt + (size_t)D * D);
  cvt_w_kernel<<<1024, 256, 0, stream>>>(W2, Wt + (size_t)2 * D * D);
  cvt_wc_kernel<<<(48 * D + 255) / 256, 256, 0, stream>>>(Wc, Wct);

  dim3 ggrid(4, (N_NODES + 127) / 128);  // n-tiles fastest for Z-tile L2 reuse
  const float* bs[3] = {b0, b1, b2};
  for (int l = 0; l < 3; ++l) {
    agg_kernel<<<N_NODES / 4, 256, 0, stream>>>(hb, row_ptr, esrc, zb);
    gemm_kernel<<<ggrid, 256, 0, stream>>>(zb, Wt + (size_t)l * D * D, bs[l], hb, N_NODES);
  }
  cls_kernel<<<(N_NODES + 63) / 64, 256, 0, stream>>>(hb, Wct, bc, out);
}

// Round 5
// 621.675 us; speedup vs baseline: 1.4782x; 1.0078x over previous
//
#include <hip/hip_runtime.h>

#define N_NODES 50000
#define N_EDGES 400000
#define D 512
#define NCLS 40
#define SCAN_BLOCKS ((N_NODES + 255) / 256)

typedef __attribute__((ext_vector_type(8))) __bf16 bf16x8;
typedef __attribute__((ext_vector_type(4))) float f32x4;
typedef __attribute__((ext_vector_type(4))) float float4v;
typedef __attribute__((ext_vector_type(8))) unsigned short ushort8v;
typedef __attribute__((ext_vector_type(4))) unsigned short ushort4v;

__device__ __forceinline__ float bf2f(unsigned short u) {
  union { unsigned int i; float f; } v; v.i = ((unsigned int)u) << 16; return v.f;
}
__device__ __forceinline__ unsigned short f2bf(float f) {
  union { float f; unsigned int i; } v; v.f = f;
  unsigned int u = v.i;
  u += 0x7fffu + ((u >> 16) & 1u);  // round-nearest-even
  return (unsigned short)(u >> 16);
}

// ---------------- CSR build ----------------
__global__ void hist_kernel(const int* __restrict__ dst, int* __restrict__ counts) {
  int e = blockIdx.x * blockDim.x + threadIdx.x;
  if (e < N_EDGES) atomicAdd(&counts[dst[e]], 1);
}

// Phase 1: per-block inclusive scan (256 elems/block); incl -> cursor buf, block sum -> bsum
__global__ __launch_bounds__(256) void scan_local_kernel(const int* __restrict__ counts,
    int* __restrict__ incl, int* __restrict__ bsum) {
  __shared__ int s[256];
  int i = blockIdx.x * 256 + threadIdx.x;
  int v = (i < N_NODES) ? counts[i] : 0;
  s[threadIdx.x] = v;
  __syncthreads();
#pragma unroll
  for (int o = 1; o < 256; o <<= 1) {
    int t = (threadIdx.x >= o) ? s[threadIdx.x - o] : 0;
    __syncthreads();
    s[threadIdx.x] += t;
    __syncthreads();
  }
  if (i < N_NODES) incl[i] = s[threadIdx.x];
  if (threadIdx.x == 255) bsum[blockIdx.x] = s[255];
}

// Phase 2: single tiny block scans the block sums -> exclusive block offsets (in place)
__global__ __launch_bounds__(256) void scan_bsum_kernel(int* __restrict__ bsum) {
  __shared__ int s[256];
  int v = (threadIdx.x < SCAN_BLOCKS) ? bsum[threadIdx.x] : 0;
  s[threadIdx.x] = v;
  __syncthreads();
#pragma unroll
  for (int o = 1; o < 256; o <<= 1) {
    int t = (threadIdx.x >= o) ? s[threadIdx.x - o] : 0;
    __syncthreads();
    s[threadIdx.x] += t;
    __syncthreads();
  }
  if (threadIdx.x < SCAN_BLOCKS) bsum[threadIdx.x] = s[threadIdx.x] - v;  // exclusive
}

// Phase 3: add block offsets; emit row_ptr and cursor (cursor buf doubled as incl)
__global__ __launch_bounds__(256) void scan_finish_kernel(const int* __restrict__ counts,
    const int* __restrict__ bsum, int* __restrict__ row_ptr, int* __restrict__ cursor) {
  int i = blockIdx.x * 256 + threadIdx.x;
  if (i < N_NODES) {
    int inc = cursor[i] + bsum[blockIdx.x];
    row_ptr[i + 1] = inc;
    cursor[i] = inc - counts[i];  // exclusive prefix = fill start
    if (i == 0) row_ptr[0] = 0;
  }
}

__global__ void fill_kernel(const int* __restrict__ src, const int* __restrict__ dst,
                            int* __restrict__ cursor, int* __restrict__ esrc) {
  int e = blockIdx.x * blockDim.x + threadIdx.x;
  if (e < N_EDGES) {
    int pos = atomicAdd(&cursor[dst[e]], 1);
    esrc[pos] = src[e];
  }
}

// ---------------- conversions ----------------
__global__ void cvt_feat_kernel(const float* __restrict__ feat, unsigned short* __restrict__ hb) {
  size_t i = (size_t)(blockIdx.x * blockDim.x + threadIdx.x) * 4;
  if (i < (size_t)N_NODES * D) {
    float4v v = *(const float4v*)&feat[i];
    ushort4v o;
    o[0] = f2bf(v[0]); o[1] = f2bf(v[1]); o[2] = f2bf(v[2]); o[3] = f2bf(v[3]);
    *(ushort4v*)&hb[i] = o;
  }
}

// Wt[n*512 + k] = bf16(W[k*512 + n])
__global__ void cvt_w_kernel(const float* __restrict__ W, unsigned short* __restrict__ Wt) {
  int i = blockIdx.x * blockDim.x + threadIdx.x;
  int n = i >> 9, k = i & 511;
  Wt[i] = f2bf(W[k * D + n]);
}

// Wct[n*512 + k] = bf16(Wc[k*40 + n]) for n<40, else 0.  [48][512] bf16, 49 KB.
__global__ void cvt_wc_kernel(const float* __restrict__ Wc, unsigned short* __restrict__ Wct) {
  int i = blockIdx.x * blockDim.x + threadIdx.x;
  if (i < 48 * D) {
    int n = i >> 9, k = i & 511;
    Wct[i] = (n < NCLS) ? f2bf(Wc[k * NCLS + n]) : (unsigned short)0;
  }
}

// ---------------- aggregation: z = h + sum_{e: dst=i} h[src[e]] ----------------
// One wave per node, lane covers 16B of the row (1 KB/wave gather). Edge loop
// unrolled 4-wide: 4 independent index loads then 4 independent row gathers in
// flight per iteration (was a serial idx->gather chain: latency-bound, 3.8 TB/s).
__global__ __launch_bounds__(256) void agg_kernel(const unsigned short* __restrict__ hb,
    const int* __restrict__ row_ptr, const int* __restrict__ esrc,
    unsigned short* __restrict__ zb) {
  int w = threadIdx.x >> 6, lane = threadIdx.x & 63;
  int node = blockIdx.x * 4 + w;
  int col = lane * 8;
  const unsigned short* hcol = hb + col;
  float acc[8];
  ushort8v v = *(const ushort8v*)&hcol[(size_t)node * D];
#pragma unroll
  for (int t = 0; t < 8; ++t) acc[t] = bf2f(v[t]);
  int s = row_ptr[node], e = row_ptr[node + 1];
  int j = s;
  for (; j + 4 <= e; j += 4) {
    int i0 = esrc[j + 0];
    int i1 = esrc[j + 1];
    int i2 = esrc[j + 2];
    int i3 = esrc[j + 3];
    ushort8v v0 = *(const ushort8v*)&hcol[(size_t)i0 * D];
    ushort8v v1 = *(const ushort8v*)&hcol[(size_t)i1 * D];
    ushort8v v2 = *(const ushort8v*)&hcol[(size_t)i2 * D];
    ushort8v v3 = *(const ushort8v*)&hcol[(size_t)i3 * D];
#pragma unroll
    for (int t = 0; t < 8; ++t) acc[t] += bf2f(v0[t]);
#pragma unroll
    for (int t = 0; t < 8; ++t) acc[t] += bf2f(v1[t]);
#pragma unroll
    for (int t = 0; t < 8; ++t) acc[t] += bf2f(v2[t]);
#pragma unroll
    for (int t = 0; t < 8; ++t) acc[t] += bf2f(v3[t]);
  }
  for (; j < e; ++j) {
    int sn = esrc[j];
    ushort8v nv = *(const ushort8v*)&hcol[(size_t)sn * D];
#pragma unroll
    for (int t = 0; t < 8; ++t) acc[t] += bf2f(nv[t]);
  }
  ushort8v o;
#pragma unroll
  for (int t = 0; t < 8; ++t) o[t] = f2bf(acc[t]);
  *(ushort8v*)&zb[(size_t)node * D + col] = o;
}

// ---------------- GEMM: Hout = relu(Z @ W + b), bf16 MFMA ----------------
__global__ __launch_bounds__(256) void gemm_kernel(
    const unsigned short* __restrict__ Z, const unsigned short* __restrict__ Wt,
    const float* __restrict__ bias, unsigned short* __restrict__ Hout, int M) {
  __shared__ unsigned short smem[128 * 132];  // 33 KB; overlays As/Bs then Cs
  unsigned short* As = smem;            // 128*32 elems
  unsigned short* Bs = smem + 4096;     // 128*32 elems
  const int n0 = blockIdx.x * 128;      // n fastest: 4 n-tiles of one m-tile adjacent
  const int m0 = blockIdx.y * 128;
  const int tid = threadIdx.x;
  const int lane = tid & 63;
  const int w = tid >> 6;
  const int wm = (w & 1) * 64;
  const int wn = (w >> 1) * 64;
  const int quad = lane >> 4;
  const int r16 = lane & 15;

  f32x4 acc[4][4];
#pragma unroll
  for (int i = 0; i < 4; ++i)
#pragma unroll
    for (int j = 0; j < 4; ++j)
      acc[i][j] = (f32x4){0.f, 0.f, 0.f, 0.f};

  const int c0 = w * 2;
  for (int kt = 0; kt < 16; ++kt) {
    __syncthreads();
    const int kbase = kt * 32;
#pragma unroll
    for (int c = 0; c < 2; ++c) {
      int chunk = c0 + c;
      int mrow = chunk * 16 + (lane >> 2);
      int kk = kbase + (lane & 3) * 8;
      int gm = m0 + mrow; if (gm > M - 1) gm = M - 1;  // clamp: garbage rows masked at store
      __builtin_amdgcn_global_load_lds(
          (__attribute__((address_space(1))) void*)(void*)(Z + (size_t)gm * D + kk),
          (__attribute__((address_space(3))) void*)(As + chunk * 512),
          16, 0, 0);
      int nrow = n0 + mrow;
      __builtin_amdgcn_global_load_lds(
          (__attribute__((address_space(1))) void*)(void*)(Wt + (size_t)nrow * D + kk),
          (__attribute__((address_space(3))) void*)(Bs + chunk * 512),
          16, 0, 0);
    }
    __syncthreads();  // drains vmcnt before use

    bf16x8 a[4], b[4];
#pragma unroll
    for (int i = 0; i < 4; ++i) {
      a[i] = *(const bf16x8*)&As[(wm + i * 16 + r16) * 32 + quad * 8];
      b[i] = *(const bf16x8*)&Bs[(wn + i * 16 + r16) * 32 + quad * 8];
    }
#pragma unroll
    for (int i = 0; i < 4; ++i)
#pragma unroll
      for (int j = 0; j < 4; ++j)
        acc[i][j] = __builtin_amdgcn_mfma_f32_16x16x32_bf16(a[i], b[j], acc[i][j], 0, 0, 0);
  }

  // ---- epilogue: bias+relu -> LDS (C tile, stride 132) -> coalesced global stores
  __syncthreads();  // all frag reads done before overwriting smem
  unsigned short* Cs = smem;
#pragma unroll
  for (int j = 0; j < 4; ++j) {
    float bv = bias[n0 + wn + j * 16 + r16];
#pragma unroll
    for (int i = 0; i < 4; ++i) {
      int crow = wm + i * 16 + quad * 4;
      int ccol = wn + j * 16 + r16;
#pragma unroll
      for (int r = 0; r < 4; ++r) {
        float vv = acc[i][j][r] + bv;
        vv = vv > 0.f ? vv : 0.f;
        Cs[(crow + r) * 132 + ccol] = f2bf(vv);
      }
    }
  }
  __syncthreads();
  // copy-out: wave w -> rows [w*32, w*32+32); per instr 4 rows x 256 B contiguous
#pragma unroll
  for (int it = 0; it < 8; ++it) {
    int row = w * 32 + it * 4 + (lane >> 4);
    int colofs = (lane & 15) * 8;
    int gm = m0 + row;
    if (gm < M) {
      ushort8v vv = *(const ushort8v*)&Cs[row * 132 + colofs];
      *(ushort8v*)&Hout[(size_t)gm * D + n0 + colofs] = vv;
    }
  }
}

// ---------------- classifier: out = h3 @ Wc + bc  (bf16 MFMA, no LDS) ----------------
__global__ __launch_bounds__(256) void cls_kernel(const unsigned short* __restrict__ hb,
    const unsigned short* __restrict__ Wct, const float* __restrict__ bc,
    float* __restrict__ out) {
  int w = threadIdx.x >> 6, lane = threadIdx.x & 63;
  int quad = lane >> 4, r16 = lane & 15;
  int nb = blockIdx.x * 64 + w * 16;
  int arow = nb + r16; if (arow > N_NODES - 1) arow = N_NODES - 1;
  f32x4 acc[3];
#pragma unroll
  for (int j = 0; j < 3; ++j) acc[j] = (f32x4){0.f, 0.f, 0.f, 0.f};
#pragma unroll 4
  for (int kt = 0; kt < 16; ++kt) {
    int kk = kt * 32 + quad * 8;
    bf16x8 a = *(const bf16x8*)&hb[(size_t)arow * D + kk];
#pragma unroll
    for (int j = 0; j < 3; ++j) {
      bf16x8 b = *(const bf16x8*)&Wct[(size_t)(j * 16 + r16) * D + kk];
      acc[j] = __builtin_amdgcn_mfma_f32_16x16x32_bf16(a, b, acc[j], 0, 0, 0);
    }
  }
  // C/D: col(n)=r16, row(m)=quad*4+reg
#pragma unroll
  for (int j = 0; j < 3; ++j) {
    int gn = j * 16 + r16;
    if (gn < NCLS) {
      float bv = bc[gn];
#pragma unroll
      for (int r = 0; r < 4; ++r) {
        int gm = nb + quad * 4 + r;
        if (gm < N_NODES) out[(size_t)gm * NCLS + gn] = acc[j][r] + bv;
      }
    }
  }
}

extern "C" void kernel_launch(void* const* d_in, const int* in_sizes, int n_in,
                              void* d_out, int out_size, void* d_ws, size_t ws_size,
                              hipStream_t stream) {
  const float* feat = (const float*)d_in[0];
  const int* src = (const int*)d_in[1];
  const int* dst = (const int*)d_in[2];
  const float* W0 = (const float*)d_in[3];
  const float* b0 = (const float*)d_in[4];
  const float* W1 = (const float*)d_in[5];
  const float* b1 = (const float*)d_in[6];
  const float* W2 = (const float*)d_in[7];
  const float* b2 = (const float*)d_in[8];
  const float* Wc = (const float*)d_in[9];
  const float* bc = (const float*)d_in[10];
  float* out = (float*)d_out;

  char* ws = (char*)d_ws;
  size_t off = 0;
  auto alloc = [&](size_t bytes) {
    char* p = ws + off;
    off += (bytes + 255) & ~(size_t)255;
    return p;
  };
  unsigned short* hb = (unsigned short*)alloc((size_t)N_NODES * D * 2);   // 51.2 MB
  unsigned short* zb = (unsigned short*)alloc((size_t)N_NODES * D * 2);   // 51.2 MB
  unsigned short* Wt = (unsigned short*)alloc((size_t)3 * D * D * 2);     // 1.5 MB
  unsigned short* Wct = (unsigned short*)alloc((size_t)48 * D * 2);       // 49 KB
  int* row_ptr = (int*)alloc((size_t)(N_NODES + 1) * 4);
  int* counts  = (int*)alloc((size_t)N_NODES * 4);
  int* cursor  = (int*)alloc((size_t)N_NODES * 4);   // doubles as incl-scan buffer
  int* esrc    = (int*)alloc((size_t)N_EDGES * 4);
  int* bsum    = (int*)alloc((size_t)256 * 4);

  // CSR build (graph static per launch; reused for all 3 layers)
  hipMemsetAsync(counts, 0, (size_t)N_NODES * 4, stream);
  hist_kernel<<<(N_EDGES + 255) / 256, 256, 0, stream>>>(dst, counts);
  scan_local_kernel<<<SCAN_BLOCKS, 256, 0, stream>>>(counts, cursor, bsum);
  scan_bsum_kernel<<<1, 256, 0, stream>>>(bsum);
  scan_finish_kernel<<<SCAN_BLOCKS, 256, 0, stream>>>(counts, bsum, row_ptr, cursor);
  fill_kernel<<<(N_EDGES + 255) / 256, 256, 0, stream>>>(src, dst, cursor, esrc);

  cvt_feat_kernel<<<(N_NODES * D / 4 + 255) / 256, 256, 0, stream>>>(feat, hb);
  cvt_w_kernel<<<1024, 256, 0, stream>>>(W0, Wt);
  cvt_w_kernel<<<1024, 256, 0, stream>>>(W1, Wt + (size_t)D * D);
  cvt_w_kernel<<<1024, 256, 0, stream>>>(W2, Wt + (size_t)2 * D * D);
  cvt_wc_kernel<<<(48 * D + 255) / 256, 256, 0, stream>>>(Wc, Wct);

  dim3 ggrid(4, (N_NODES + 127) / 128);  // n-tiles fastest for Z-tile L2 reuse
  const float* bs[3] = {b0, b1, b2};
  for (int l = 0; l < 3; ++l) {
    agg_kernel<<<N_NODES / 4, 256, 0, stream>>>(hb, row_ptr, esrc, zb);
    gemm_kernel<<<ggrid, 256, 0, stream>>>(zb, Wt + (size_t)l * D * D, bs[l], hb, N_NODES);
  }
  cls_kernel<<<(N_NODES + 63) / 64, 256, 0, stream>>>(hb, Wct, bc, out);
}